// Round 8
// baseline (3783.578 us; speedup 1.0000x reference)
//
#include <hip/hip_runtime.h>

#define DEVINL __device__ __forceinline__

namespace {
constexpr int B = 256, T = 128, F = 128, H = 512;
constexpr int NBLK = 512;        // 2 blocks per row: column-split halves
constexpr int NTHR = 512;

// workspace layout in 4-byte words (weights identical to round 7)
constexpr size_t OFF_NUM    = 0;                         // [128] loss numerators
constexpr size_t OFF_DEN    = 128;                       // [128] denominators
constexpr size_t OFF_WQCC   = 256;                       // gates cc|m i8x4 [64 k4][2048 col]
constexpr size_t OFF_WQH    = OFF_WQCC + 64 * 2048;      // gates h    i8x4 [128 k4][2048 col]
constexpr size_t OFF_FSCC   = OFF_WQH + 128 * 2048;      // [2048] colmax/(127*15.875)
constexpr size_t OFF_FSCHG  = OFF_FSCC + 2048;           // [2048] colmax/16129
constexpr size_t OFF_HISTQ  = OFF_FSCHG + 2048;          // hist i8x4 [128 k4][128 f]
constexpr size_t OFF_FSCH   = OFF_HISTQ + 128 * 128;     // [128] colmax/16129
constexpr size_t OFF_TD2    = OFF_FSCH + 128;            // td_h f16x2 [64 k2][512 j]
constexpr size_t OFF_FEAT2  = OFF_TD2 + 64 * 512;        // feat f16x2 [64 k2][128 f]
constexpr size_t OFF_WC2    = OFF_FEAT2 + 64 * 128;      // wc   f16x2 [128 k2][128 f]
constexpr size_t OFF_BSUM   = OFF_WC2 + 128 * 128;       // [2048] b_ih+b_hh gate-interleaved
constexpr size_t OFF_FDIAG  = OFF_BSUM + 2048;           // [128] f16-rounded feat diag
// fence-free exchange region (u64 tagged words; offsets even -> 8B aligned)
constexpr size_t OFF_HXW    = OFF_FDIAG + 128;           // u64 [256 rows][128 hq words]
constexpr size_t OFF_XCW    = OFF_HXW + 256 * 128 * 2;   // u64 [256][64 xc2 words]
constexpr size_t OFF_CCW    = OFF_XCW + 256 * 64 * 2;    // u64 [256][32 cc-actq words]
constexpr size_t WS_WORDS   = OFF_CCW + 256 * 32 * 2;    // ~2.2 MB (<8.2 MB known-good)

constexpr float ACT_S  = 15.875f;                // cc|m activation scale (clamp +-8)
constexpr float DEQ_CC = 1.f / (127.f * 15.875f);
constexpr float DEQ_H  = 1.f / (127.f * 127.f);
constexpr unsigned SPIN_CAP = 1u << 17;          // ~100x expected max skew; dead-flag after
}

typedef _Float16 h2_t __attribute__((ext_vector_type(2)));

DEVINL h2_t as_h2(unsigned u) { union { unsigned u; h2_t h; } c; c.u = u; return c.h; }
DEVINL unsigned pack2(float a, float b) {
  union { h2_t h; unsigned u; } c;
  c.h = h2_t{(_Float16)a, (_Float16)b};
  return c.u;
}

#if defined(__has_builtin)
#if __has_builtin(__builtin_amdgcn_fdot2)
#define HAVE_FDOT2 1
#endif
#if __has_builtin(__builtin_amdgcn_sdot4)
#define HAVE_SDOT4 1
#endif
#endif
#ifdef HAVE_FDOT2
DEVINL float fdot2(h2_t a, h2_t b, float c) { return __builtin_amdgcn_fdot2(a, b, c, false); }
#else
DEVINL float fdot2(h2_t a, h2_t b, float c) {
  return fmaf((float)a.x, (float)b.x, fmaf((float)a.y, (float)b.y, c));
}
#endif
#ifdef HAVE_SDOT4
DEVINL int sdot4(int a, int b, int c) { return __builtin_amdgcn_sdot4(a, b, c, false); }
#else
DEVINL int sdot4(int a, int b, int c) {
  return c + ((a << 24) >> 24) * ((b << 24) >> 24)
           + ((a << 16) >> 24) * ((b << 16) >> 24)
           + ((a << 8) >> 24) * ((b << 8) >> 24)
           + (a >> 24) * (b >> 24);
}
#endif

DEVINL float fast_sig(float x)  { return 1.f / (1.f + __expf(-x)); }
DEVINL float fast_tanh(float x) { return 1.f - 2.f / (1.f + __expf(2.f * x)); }

DEVINL float wave_sum(float v) {
#pragma unroll
  for (int s = 32; s; s >>= 1) v += __shfl_down(v, s, 64);
  return v;
}
DEVINL float wave_max(float v) {
#pragma unroll
  for (int s = 32; s; s >>= 1) v = fmaxf(v, __shfl_down(v, s, 64));
  return v;
}

// tagged u64 exchange: value in low 32, step tag in high 32. Relaxed device
// scope -> single-address coherent cross-XCD, NO acquire fence (no L2 inval).
DEVINL void ex_store(unsigned long long* p, unsigned tag, unsigned val) {
  __hip_atomic_store(p, ((unsigned long long)tag << 32) | (unsigned long long)val,
                     __ATOMIC_RELAXED, __HIP_MEMORY_SCOPE_AGENT);
}
DEVINL unsigned ex_load(unsigned long long* p, unsigned tag, int* dead) {
  if (*dead) return 0u;
  unsigned long long v = 0; unsigned n = 0;
  for (;;) {
    v = __hip_atomic_load(p, __ATOMIC_RELAXED, __HIP_MEMORY_SCOPE_AGENT);
    if ((unsigned)(v >> 32) == tag) return (unsigned)v;
    if (++n > SPIN_CAP) { *dead = 1; return (unsigned)v; }   // tripwire, no hang
  }
}

// ---- prep: f16 tables + biases (TD2, FEAT2, WC2, BSUM, FDIAG) ----
__global__ void prep_f16(const float* __restrict__ td_h_W, const float* __restrict__ feat_W,
                         const float* __restrict__ wc_W, const float* __restrict__ b_ih,
                         const float* __restrict__ b_hh,
                         unsigned* __restrict__ wsu, float* __restrict__ wsf) {
  int idx = blockIdx.x * blockDim.x + threadIdx.x;
  if (idx < 32768) {                           // TD2 [64][512]
    const int k2 = idx >> 9, j = idx & 511;
    wsu[OFF_TD2 + idx] = pack2(td_h_W[j * 128 + 2 * k2], td_h_W[j * 128 + 2 * k2 + 1]);
  } else if (idx < 40960) {                    // FEAT2 [64][128]
    const int i = idx - 32768, k2 = i >> 7, f = i & 127;
    wsu[OFF_FEAT2 + i] = pack2(feat_W[f * 128 + 2 * k2], feat_W[f * 128 + 2 * k2 + 1]);
  } else if (idx < 57344) {                    // WC2 [128][128]
    const int i = idx - 40960, k2 = i >> 7, f = i & 127;
    wsu[OFF_WC2 + i] = pack2(wc_W[f * 256 + 2 * k2], wc_W[f * 256 + 2 * k2 + 1]);
  } else if (idx < 59392) {                    // BSUM [2048]
    const int i = idx - 57344, unit = i >> 2, g = i & 3;
    wsf[OFF_BSUM + i] = b_ih[g * 512 + unit] + b_hh[g * 512 + unit];
  } else if (idx < 59520) {                    // FDIAG [128]
    const int f = idx - 59392;
    wsf[OFF_FDIAG + f] = (float)(_Float16)feat_W[f * 129];
  }
}

// ---- prep: i8 quant of W_ih columns (K=256, cc|m part), per-column scale ----
__global__ void prep_quant_wih(const float* __restrict__ Wih,
                               unsigned* __restrict__ wq, float* __restrict__ fscc) {
  const int col = blockIdx.x;                  // 2048 = 4*unit+gate
  const int unit = col >> 2, g = col & 3;
  const float* src = Wih + (size_t)(g * 512 + unit) * 256;
  const int t = threadIdx.x;                   // 64 threads, 4 k each
  const float4 v = ((const float4*)src)[t];
  float mx = fmaxf(fmaxf(fabsf(v.x), fabsf(v.y)), fmaxf(fabsf(v.z), fabsf(v.w)));
  mx = wave_max(mx);
  mx = __shfl(mx, 0, 64);
  const float s = (mx > 0.f) ? 127.f / mx : 0.f;
  const int q0 = __float2int_rn(v.x * s), q1 = __float2int_rn(v.y * s);
  const int q2 = __float2int_rn(v.z * s), q3 = __float2int_rn(v.w * s);
  wq[t * 2048 + col] =
      (q0 & 0xFF) | ((q1 & 0xFF) << 8) | ((q2 & 0xFF) << 16) | ((q3 & 0xFF) << 24);
  if (t == 0) fscc[col] = mx * DEQ_CC;
}

// ---- prep: i8 quant of W_hh columns (K=512, h part) ----
__global__ void prep_quant_whh(const float* __restrict__ Whh,
                               unsigned* __restrict__ wq, float* __restrict__ fschg) {
  const int col = blockIdx.x;
  const int unit = col >> 2, g = col & 3;
  const float* src = Whh + (size_t)(g * 512 + unit) * 512;
  const int t = threadIdx.x;                   // 128 threads, 4 k each
  const float4 v = ((const float4*)src)[t];
  float mx = fmaxf(fmaxf(fabsf(v.x), fabsf(v.y)), fmaxf(fabsf(v.z), fabsf(v.w)));
  mx = wave_max(mx);
  __shared__ float wm[2];
  if ((t & 63) == 0) wm[t >> 6] = mx;
  __syncthreads();
  const float maxv = fmaxf(wm[0], wm[1]);
  const float s = (maxv > 0.f) ? 127.f / maxv : 0.f;
  const int q0 = __float2int_rn(v.x * s), q1 = __float2int_rn(v.y * s);
  const int q2 = __float2int_rn(v.z * s), q3 = __float2int_rn(v.w * s);
  wq[t * 2048 + col] =
      (q0 & 0xFF) | ((q1 & 0xFF) << 8) | ((q2 & 0xFF) << 16) | ((q3 & 0xFF) << 24);
  if (t == 0) fschg[col] = maxv * DEQ_H;
}

// ---- prep: i8 quant of hist_W rows (K=512) ----
__global__ void prep_quant_hist(const float* __restrict__ histW,
                                unsigned* __restrict__ histq, float* __restrict__ fsch) {
  const int f = blockIdx.x;                    // 128
  const float* src = histW + (size_t)f * 512;
  const int t = threadIdx.x;                   // 128 threads
  const float4 v = ((const float4*)src)[t];
  float mx = fmaxf(fmaxf(fabsf(v.x), fabsf(v.y)), fmaxf(fabsf(v.z), fabsf(v.w)));
  mx = wave_max(mx);
  __shared__ float wm[2];
  if ((t & 63) == 0) wm[t >> 6] = mx;
  __syncthreads();
  const float maxv = fmaxf(wm[0], wm[1]);
  const float s = (maxv > 0.f) ? 127.f / maxv : 0.f;
  const int q0 = __float2int_rn(v.x * s), q1 = __float2int_rn(v.y * s);
  const int q2 = __float2int_rn(v.z * s), q3 = __float2int_rn(v.w * s);
  histq[t * 128 + f] =
      (q0 & 0xFF) | ((q1 & 0xFF) << 8) | ((q2 & 0xFF) << 16) | ((q3 & 0xFF) << 24);
  if (t == 0) fsch[f] = maxv * DEQ_H;
}

// ---- main: 512 blocks x 512 threads; blocks (2r,2r+1) column-split row r.
//      Each block streams HALF of every weight table; recurrent halves are
//      exchanged via tagged u64 relaxed device atomics (no fences). ----
__global__ void __launch_bounds__(512, 4) rits_batch(
    const float* __restrict__ x, const float* __restrict__ m, const float* __restrict__ d,
    const float* __restrict__ tx, const float* __restrict__ tmask,
    const float* __restrict__ td_h_b, const float* __restrict__ td_x_W,
    const float* __restrict__ td_x_b, const float* __restrict__ hist_b,
    const float* __restrict__ feat_b, const float* __restrict__ wc_b,
    const unsigned* __restrict__ wsu, const float* __restrict__ wsf,
    float* __restrict__ num, float* __restrict__ den, float* __restrict__ out)
{
  const int tid = threadIdx.x;
  const int row = blockIdx.x >> 1;
  const int p   = blockIdx.x & 1;              // which half this block owns
  const int pw  = 1 - p;
  const int ob  = p * 256;                     // own unit base (256 units)
  const int ofb = p * 64;                      // own f base (64 features)
  const int ul  = tid & 255;                   // unit-local (phase C/I)

  unsigned long long* HXW = (unsigned long long*)(wsf + OFF_HXW) + (size_t)row * 128;
  unsigned long long* XCW = (unsigned long long*)(wsf + OFF_XCW) + (size_t)row * 64;
  unsigned long long* CCW = (unsigned long long*)(wsf + OFF_CCW) + (size_t)row * 32;

  __shared__ unsigned actq[64];                // cc i8 words 0..31 | m i8 32..63 (full f)
  __shared__ int hq[128];                      // decayed h i8x4, full 512 units
  __shared__ unsigned d2[64];                  // d f16 pairs
  __shared__ unsigned xc2[64];                 // x_c f16 pairs (full f)
  __shared__ unsigned gxm2[128];               // gx pairs 0..63 | m pairs 64..127 (full f)
  __shared__ float xrow[128], mrow[128], drow[128], txrow[128], evrow[128], gx_ls[128];
  __shared__ int   partI[512];
  __shared__ float partZ[512], partA[512];
  __shared__ int4  partH[256];
  __shared__ int dead;

  // per-thread persistent constants (own half)
  const float4 bs    = *(const float4*)(wsf + OFF_BSUM + 4 * (ob + ul));
  const float4 fscc4 = *(const float4*)(wsf + OFF_FSCC + 4 * (ob + ul));
  const float4 fsch4 = *(const float4*)(wsf + OFF_FSCHG + 4 * (ob + ul));
  const float tdb = td_h_b[ob + ul];
  const int fc = ofb + (tid & 63);
  const float hb = hist_b[fc], fb = feat_b[fc], wb = wc_b[fc];
  const float fd = wsf[OFF_FDIAG + fc];
  const float fsch_f = wsf[OFF_FSCH + fc];

  float h0 = 0.f, c0 = 0.f;                    // recurrent state (tid<256, unit ob+tid)
  if (tid == 0) dead = 0;

  for (int t = 0; t < T; ++t) {
    const unsigned tag = (unsigned)(t + 1);
    const int base = (row * T + t) * F;
    float xh_r = 0.f, xc_r = 0.f;              // live E' -> G' (tid<64)

    // ---- A: stage inputs + packs that depend only on inputs (928 items) ----
    for (int i = tid; i < 928; i += 512) {
      if (i < 640) {
        const int a = i >> 7, f = i & 127;
        const float v = (a == 0 ? x[base + f] : a == 1 ? m[base + f] : a == 2 ? d[base + f]
                         : a == 3 ? tx[base + f] : tmask[base + f]);
        if      (a == 0) xrow[f]  = v;
        else if (a == 1) mrow[f]  = v;
        else if (a == 2) drow[f]  = v;
        else if (a == 3) txrow[f] = v;
        else             evrow[f] = v;
      } else if (i < 704) {
        const int k2 = i - 640;
        d2[k2] = pack2(d[base + 2 * k2], d[base + 2 * k2 + 1]);
      } else if (i < 768) {
        const int q = i - 704;
        gxm2[64 + q] = pack2(m[base + 2 * q], m[base + 2 * q + 1]);
      } else if (i < 800) {
        const int w = i - 768;
        const int b4 = base + 4 * w;
        const int q0 = __float2int_rn(m[b4] * ACT_S);
        const int q1 = __float2int_rn(m[b4 + 1] * ACT_S);
        const int q2 = __float2int_rn(m[b4 + 2] * ACT_S);
        const int q3 = __float2int_rn(m[b4 + 3] * ACT_S);
        actq[32 + w] =
            (q0 & 0xFF) | ((q1 & 0xFF) << 8) | ((q2 & 0xFF) << 16) | ((q3 & 0xFF) << 24);
      } else {
        const int f = i - 800;                 // gamma_x (diag), full f
        gx_ls[f] = __expf(-fmaxf(fmaf(d[base + f], td_x_W[f * 129], td_x_b[f]), 0.f));
      }
    }
    __syncthreads();

    // ---- C: gamma_h (own 256 units), decay reg h, pack+publish own hq words;
    //         partner hq words pulled via tagged atomics ----
    if (tid < 256) {
      float g0 = tdb;
#pragma unroll 8
      for (int k2 = 0; k2 < 64; ++k2)
        g0 = fdot2(as_h2(wsu[OFF_TD2 + (k2 << 9) + ob + tid]), as_h2(d2[k2]), g0);
      h0 *= __expf(-fmaxf(g0, 0.f));
      int q = __float2int_rn(h0 * 127.f);
      const int a1 = __shfl_down(q, 1, 64), a2 = __shfl_down(q, 2, 64), a3 = __shfl_down(q, 3, 64);
      if ((tid & 3) == 0) {
        const int wd = p * 64 + (tid >> 2);
        const unsigned wv =
            (q & 0xFF) | ((a1 & 0xFF) << 8) | ((a2 & 0xFF) << 16) | ((a3 & 0xFF) << 24);
        hq[wd] = (int)wv;
        ex_store(HXW + wd, tag, wv);
      }
    } else if (tid < 320) {
      const int wd = pw * 64 + (tid - 256);
      hq[wd] = (int)ex_load(HXW + wd, tag, &dead);
    }
    __syncthreads();

    // ---- E: x_hist partials (i8, own 64 f, K=512 split 8 ways) ----
    {
      const int kq = tid >> 6;
      int isum = 0;
#pragma unroll 8
      for (int k = 0; k < 16; ++k) {
        const int k4 = kq * 16 + k;
        isum = sdot4((int)wsu[OFF_HISTQ + (k4 << 7) + fc], hq[k4], isum);
      }
      partI[tid] = isum;
    }
    __syncthreads();

    // ---- E': reduce x_hist; x_c; publish own xc2 words; pull partner's;
    //          pack gx pairs ----
    if (tid < 64) {
      int isum = 0;
#pragma unroll
      for (int i = 0; i < 8; ++i) isum += partI[tid + 64 * i];
      xh_r = fmaf((float)isum, fsch_f, hb);
      const float mv = mrow[fc];
      xc_r = mv * xrow[fc] + (1.f - mv) * xh_r;
      const float xcs = __shfl_down(xc_r, 1, 64);
      if (!(tid & 1)) {
        const int idx = p * 32 + (tid >> 1);
        const unsigned wv = pack2(xc_r, xcs);
        xc2[idx] = wv;
        ex_store(XCW + idx, tag, wv);
      }
    } else if (tid < 96) {
      const int idx = pw * 32 + (tid - 64);
      xc2[idx] = ex_load(XCW + idx, tag, &dead);
    } else if (tid >= 128 && tid < 192) {
      const int q = tid - 128;
      gxm2[q] = pack2(gx_ls[2 * q], gx_ls[2 * q + 1]);
    }
    __syncthreads();

    // ---- G: feat + alpha partials (own 64 f, K split 8 ways) ----
    {
      const int kq = tid >> 6;
      float zs = 0.f;
#pragma unroll 8
      for (int k = 0; k < 8; ++k) {
        const int k2 = kq * 8 + k;
        zs = fdot2(as_h2(wsu[OFF_FEAT2 + (k2 << 7) + fc]), as_h2(xc2[k2]), zs);
      }
      partZ[tid] = zs;
      float as = 0.f;
#pragma unroll 8
      for (int k = 0; k < 16; ++k) {
        const int k2 = kq * 16 + k;
        as = fdot2(as_h2(wsu[OFF_WC2 + (k2 << 7) + fc]), as_h2(gxm2[k2]), as);
      }
      partA[tid] = as;
    }
    __syncthreads();

    // ---- G': z_h, alpha, c_h, c_c, out, loss; publish own cc words; pull ----
    if (tid < 64) {
      float z = fb, aa = wb;
#pragma unroll
      for (int i = 0; i < 8; ++i) { z += partZ[tid + 64 * i]; aa += partA[tid + 64 * i]; }
      z -= xc_r * fd;                          // remove diagonal
      const float al = fast_sig(aa);
      const float ch = al * z + (1.f - al) * xh_r;
      const float mv = mrow[fc];
      const float cc = mv * xrow[fc] + (1.f - mv) * ch;
      out[base + fc] = cc;
      const float ev = evrow[fc], tg = txrow[fc];
      const float e1 = xh_r - tg, e2 = z - tg, e3 = ch - tg;
      const float s1 = wave_sum(ev * (e1 * e1 + e2 * e2 + e3 * e3));
      const float s2 = wave_sum(ev);
      if (tid == 0) { atomicAdd(&num[t], s1); atomicAdd(&den[t], s2); }
      int qc = __float2int_rn(fminf(fmaxf(cc, -8.f), 8.f) * ACT_S);
      const int c1s = __shfl_down(qc, 1, 64), c2s = __shfl_down(qc, 2, 64), c3s = __shfl_down(qc, 3, 64);
      if (!(tid & 3)) {
        const int idx = p * 16 + (tid >> 2);
        const unsigned wv =
            (qc & 0xFF) | ((c1s & 0xFF) << 8) | ((c2s & 0xFF) << 16) | ((c3s & 0xFF) << 24);
        actq[idx] = wv;
        ex_store(CCW + idx, tag, wv);
      }
    } else if (tid < 80) {
      const int idx = pw * 16 + (tid - 64);
      actq[idx] = ex_load(CCW + idx, tag, &dead);
    }
    __syncthreads();

    // ---- I: gates for own 1024 cols, K split 2 ways; LSTM update ----
    {
      const int kh = tid >> 8;
      const unsigned* wq = wsu + OFF_WQCC + 4 * (ob + ul);
      const unsigned* wh = wsu + OFF_WQH  + 4 * (ob + ul);
      int ci = 0, cf = 0, cg = 0, co = 0;
      int hi = 0, hf = 0, hg = 0, ho = 0;
      if (kh == 0) {
#pragma unroll 8
        for (int w = 0; w < 64; ++w) {
          const uint4 W = *(const uint4*)(wq + (w << 11));
          const int a0 = (int)actq[w];
          ci = sdot4((int)W.x, a0, ci); cf = sdot4((int)W.y, a0, cf);
          cg = sdot4((int)W.z, a0, cg); co = sdot4((int)W.w, a0, co);
        }
#pragma unroll 8
        for (int k = 0; k < 32; ++k) {
          const uint4 W = *(const uint4*)(wh + (k << 11));
          const int a0 = hq[k];
          hi = sdot4((int)W.x, a0, hi); hf = sdot4((int)W.y, a0, hf);
          hg = sdot4((int)W.z, a0, hg); ho = sdot4((int)W.w, a0, ho);
        }
      } else {
#pragma unroll 8
        for (int k = 32; k < 128; ++k) {
          const uint4 W = *(const uint4*)(wh + (k << 11));
          const int a0 = hq[k];
          hi = sdot4((int)W.x, a0, hi); hf = sdot4((int)W.y, a0, hf);
          hg = sdot4((int)W.z, a0, hg); ho = sdot4((int)W.w, a0, ho);
        }
        partH[ul] = int4{hi, hf, hg, ho};
      }
      __syncthreads();
      if (tid < 256) {
        const int4 ph = partH[ul];
        const float ai = bs.x + fscc4.x * (float)ci + fsch4.x * (float)(hi + ph.x);
        const float af = bs.y + fscc4.y * (float)cf + fsch4.y * (float)(hf + ph.y);
        const float ag = bs.z + fscc4.z * (float)cg + fsch4.z * (float)(hg + ph.z);
        const float ao = bs.w + fscc4.w * (float)co + fsch4.w * (float)(ho + ph.w);
        const float ig = fast_sig(ai), fg = fast_sig(af);
        const float gg = fast_tanh(ag), og = fast_sig(ao);
        c0 = fg * c0 + ig * gg;
        h0 = og * fast_tanh(c0);
      }
    }
    __syncthreads();   // protect LDS from next step's writers
  }
}

__global__ void finalize(const float* __restrict__ num, const float* __restrict__ den,
                         float* __restrict__ out) {
  __shared__ float red[2];
  const int t = threadIdx.x;     // 128 threads
  float v = num[t] / (den[t] + 1e-8f);
  v = wave_sum(v);
  if ((t & 63) == 0) red[t >> 6] = v;
  __syncthreads();
  if (t == 0) out[(size_t)B * T * F] = (red[0] + red[1]) / (float)T;
}

extern "C" void kernel_launch(void* const* d_in, const int* in_sizes, int n_in,
                              void* d_out, int out_size, void* d_ws, size_t ws_size,
                              hipStream_t stream) {
  const float* x      = (const float*)d_in[0];
  const float* m      = (const float*)d_in[1];
  const float* d      = (const float*)d_in[2];
  const float* tx     = (const float*)d_in[3];
  const float* tmask  = (const float*)d_in[4];
  const float* td_h_W = (const float*)d_in[5];
  const float* td_h_b = (const float*)d_in[6];
  const float* td_x_W = (const float*)d_in[7];
  const float* td_x_b = (const float*)d_in[8];
  const float* hist_W = (const float*)d_in[9];
  const float* hist_b = (const float*)d_in[10];
  const float* feat_W = (const float*)d_in[11];
  const float* feat_b = (const float*)d_in[12];
  const float* wc_W   = (const float*)d_in[13];
  const float* wc_b   = (const float*)d_in[14];
  const float* W_ih   = (const float*)d_in[15];
  const float* W_hh   = (const float*)d_in[16];
  const float* b_ih   = (const float*)d_in[17];
  const float* b_hh   = (const float*)d_in[18];

  float*    wsf = (float*)d_ws;
  unsigned* wsu = (unsigned*)d_ws;
  float*    out = (float*)d_out;

  if (ws_size < WS_WORDS * 4) return;   // OOB tripwire

  hipMemsetAsync(d_ws, 0, 256 * sizeof(float), stream);                 // num/den
  hipMemsetAsync(wsf + OFF_HXW, 0, (WS_WORDS - OFF_HXW) * 4, stream);   // exchange tags
  prep_f16<<<dim3((59520 + 255) / 256), dim3(256), 0, stream>>>(
      td_h_W, feat_W, wc_W, b_ih, b_hh, wsu, wsf);
  prep_quant_wih<<<dim3(2048), dim3(64), 0, stream>>>(
      W_ih, wsu + OFF_WQCC, wsf + OFF_FSCC);
  prep_quant_whh<<<dim3(2048), dim3(128), 0, stream>>>(
      W_hh, wsu + OFF_WQH, wsf + OFF_FSCHG);
  prep_quant_hist<<<dim3(128), dim3(128), 0, stream>>>(
      hist_W, wsu + OFF_HISTQ, wsf + OFF_FSCH);
  rits_batch<<<dim3(NBLK), dim3(NTHR), 0, stream>>>(
      x, m, d, tx, tmask, td_h_b, td_x_W, td_x_b, hist_b, feat_b, wc_b,
      wsu, wsf, wsf + OFF_NUM, wsf + OFF_DEN, out);
  finalize<<<dim3(1), dim3(128), 0, stream>>>(wsf + OFF_NUM, wsf + OFF_DEN, out);
}